// Round 6
// baseline (303.614 us; speedup 1.0000x reference)
//
#include <hip/hip_runtime.h>
#include <math.h>

// CognitiveRouter: module routing (4) + grouped expert routing (16), combined
// hierarchical probs, top-4 + renorm.  T=32768, D=1536, fp32 in/out.
//
// R6 (R5 post-mortem: ~106us, LDS-pipe-bound -- 21 ds_read_b128 per 80
// wave-FMAs; broadcast b128 costs full return bandwidth ~12cyc, and the CU
// has 4 VALU SIMDs but one LDS pipe -> LDS 3x oversubscribed).
// Change: register-block 2 ROWS PER LANE.  Per g-step: 22 LDS reads per
// 160 wave-FMAs (2x better LDS:VALU ratio), 40 independent acc chains.
//  - 128 rows/block, 512 thr (8 waves, split-K 8), grid 256 = 1 block/CU.
//  - CHUNK 8, row stride 12 floats = 3x16B (odd) -> conflict-free b128.
//  - #pragma unroll 1 on chunk loop (R4's hoist->spill guard).
//  - Exchange/epilogue runs twice (row half r0, then r1) to keep LDS <=64KB.

#define DD 1536
#define NM 4
#define NE 16
#define NW 20          // 16 expert rows + 4 module rows
#define RPB 128        // rows per block (2 per lane)
#define NWAVE 8        // split-K ways
#define NTHR (NWAVE * 64)
#define CPW 192        // cols per wave (DD / 8)
#define CHUNK 8        // cols staged per iteration
#define STRIDE 12      // CHUNK + 4: 3x16B rows -> conflict-free ds_*_b128
#define HS_FLOATS (RPB * STRIDE)            // 1536
#define W_FLOATS  (NW * STRIDE)             // 240
#define WAVE_REG  (HS_FLOATS + W_FLOATS)    // 1776 floats per wave region

typedef float v4f __attribute__((ext_vector_type(4)));

union SharedMem {
    float stage[NWAVE * WAVE_REG];   // 14208 floats = 56832 B
    float xch[NW * NTHR];            // 10240 floats
};

__device__ __forceinline__ void epilogue(const float* __restrict__ xch,
                                         int lane, int row,
                                         float* __restrict__ out, int T)
{
    float logit[NW];
#pragma unroll
    for (int e = 0; e < NW; e++) {
        float s = 0.f;
#pragma unroll
        for (int w = 0; w < NWAVE; w++)
            s += xch[e * NTHR + w * 64 + lane];
        logit[e] = s;
    }

    // module softmax over logit[16..19]
    float mmax = logit[16];
#pragma unroll
    for (int m = 1; m < NM; m++) mmax = fmaxf(mmax, logit[16 + m]);
    float mexp[NM], msum = 0.f;
#pragma unroll
    for (int m = 0; m < NM; m++) { mexp[m] = expf(logit[16 + m] - mmax); msum += mexp[m]; }

    // per-module expert softmax, combined probs
    float comb[NE];
#pragma unroll
    for (int m = 0; m < NM; m++) {
        float mprob = mexp[m] / msum;
        float emax = logit[m * 4];
#pragma unroll
        for (int j = 1; j < 4; j++) emax = fmaxf(emax, logit[m * 4 + j]);
        float ee[4], esum = 0.f;
#pragma unroll
        for (int j = 0; j < 4; j++) { ee[j] = expf(logit[m * 4 + j] - emax); esum += ee[j]; }
        float scale = mprob / esum;
#pragma unroll
        for (int j = 0; j < 4; j++) comb[m * 4 + j] = ee[j] * scale;
    }

    float4* cw = (float4*)(out + (size_t)row * 16);
    cw[0] = make_float4(comb[0],  comb[1],  comb[2],  comb[3]);
    cw[1] = make_float4(comb[4],  comb[5],  comb[6],  comb[7]);
    cw[2] = make_float4(comb[8],  comb[9],  comb[10], comb[11]);
    cw[3] = make_float4(comb[12], comb[13], comb[14], comb[15]);

    // top-4, descending, strict > so lowest index wins ties (lax.top_k)
    float tv[4]; int ti[4];
    unsigned mask = 0;
#pragma unroll
    for (int k = 0; k < 4; k++) {
        float best = -1.f; int bi = 0;
#pragma unroll
        for (int i = 0; i < NE; i++) {
            bool avail = !((mask >> i) & 1u);
            if (avail && comb[i] > best) { best = comb[i]; bi = i; }
        }
        tv[k] = best; ti[k] = bi; mask |= 1u << bi;
    }
    float s = tv[0] + tv[1] + tv[2] + tv[3] + 1e-8f;

    const size_t wOff = (size_t)T * 16;          // top_k_weights region
    const size_t iOff = (size_t)T * 20;          // top_k_indices region
    float4* ww = (float4*)(out + wOff + (size_t)row * 4);
    *ww = make_float4(tv[0] / s, tv[1] / s, tv[2] / s, tv[3] / s);
    float4* iw = (float4*)(out + iOff + (size_t)row * 4);
    *iw = make_float4((float)ti[0], (float)ti[1], (float)ti[2], (float)ti[3]);
}

__global__ __launch_bounds__(NTHR)
void router_kernel(const float* __restrict__ hs,
                   const float* __restrict__ Wm,
                   const float* __restrict__ We,
                   float* __restrict__ out,
                   int T)
{
    __shared__ SharedMem sm;
    const int tid  = threadIdx.x;
    const int wv   = tid >> 6;
    const int lane = tid & 63;
    const int rowBlock = blockIdx.x * RPB;
    const int colStart = wv * CPW;

    float acc0[NW], acc1[NW];
#pragma unroll
    for (int e = 0; e < NW; e++) { acc0[e] = 0.f; acc1[e] = 0.f; }

    // hs staging map: 2 lanes cover one row's 8-col chunk (2x float4);
    // lane -> (row srow + 32i, col group scol).
    const int srow = lane >> 1;          // 0..31
    const int scol = (lane & 1) << 2;    // 0 or 4
    const float* hsBase = hs + (size_t)(rowBlock + srow) * DD + colStart + scol;
    float* myHs = &sm.stage[wv * WAVE_REG];
    float* myW  = myHs + HS_FLOATS;

    // weight staging map: 20 rows x 2 col-groups = 40 float4 slots, lanes<40
    const int wrow = (lane >> 1) < 20 ? (lane >> 1) : 19;   // clamp for ptr
    const int wgrp = (lane & 1) << 2;
    const float* wPtr = ((wrow < 16) ? (We + (size_t)wrow * DD)
                                     : (Wm + (size_t)(wrow - 16) * DD))
                        + colStart + wgrp;
    const bool wLane = (lane < 40);

    // ---- prefetch chunk 0 ----
    v4f hbuf[4], wbuf;
#pragma unroll
    for (int i = 0; i < 4; i++)
        hbuf[i] = *(const v4f*)(hsBase + (size_t)(i * 32) * DD);
    if (wLane) wbuf = *(const v4f*)(wPtr);

#pragma unroll 1
    for (int c = 0; c < CPW; c += CHUNK) {
        // ---- commit prefetched tiles to wave-private LDS ----
#pragma unroll
        for (int i = 0; i < 4; i++)
            *(v4f*)&myHs[(srow + i * 32) * STRIDE + scol] = hbuf[i];
        if (wLane) *(v4f*)&myW[wrow * STRIDE + wgrp] = wbuf;

        // ---- prefetch next chunk while computing this one ----
        if (c + CHUNK < CPW) {
            const int cn = c + CHUNK;
#pragma unroll
            for (int i = 0; i < 4; i++)
                hbuf[i] = *(const v4f*)(hsBase + (size_t)(i * 32) * DD + cn);
            if (wLane) wbuf = *(const v4f*)(wPtr + cn);
        }

        // ---- compute: 2 g-steps x (2 hs reads + 20 w reads + 160 FMA) ----
#pragma unroll
        for (int g = 0; g < 2; g++) {
            v4f h0 = *(const v4f*)&myHs[lane * STRIDE + (g << 2)];
            v4f h1 = *(const v4f*)&myHs[(lane + 64) * STRIDE + (g << 2)];
#pragma unroll
            for (int e = 0; e < NW; e++) {
                v4f w = *(const v4f*)&myW[e * STRIDE + (g << 2)]; // broadcast
                acc0[e] += h0.x * w.x + h0.y * w.y + h0.z * w.z + h0.w * w.w;
                acc1[e] += h1.x * w.x + h1.y * w.y + h1.z * w.z + h1.w * w.w;
            }
        }
        // no barrier: wave-private staging, wave program order suffices
    }

    // ---- split-K exchange + epilogue, two row halves ----
    __syncthreads();   // staging regions dead for ALL waves before overlay
#pragma unroll
    for (int e = 0; e < NW; e++) sm.xch[e * NTHR + tid] = acc0[e];
    __syncthreads();
    if (wv == 0) epilogue(sm.xch, lane, rowBlock + lane, out, T);
    __syncthreads();   // wave 0 finished reading pass-1 data
#pragma unroll
    for (int e = 0; e < NW; e++) sm.xch[e * NTHR + tid] = acc1[e];
    __syncthreads();
    if (wv == 0) epilogue(sm.xch, lane, rowBlock + 64 + lane, out, T);
}

extern "C" void kernel_launch(void* const* d_in, const int* in_sizes, int n_in,
                              void* d_out, int out_size, void* d_ws, size_t ws_size,
                              hipStream_t stream)
{
    const float* hs = (const float*)d_in[0];   // (T, 1536)
    const float* Wm = (const float*)d_in[1];   // (4, 1536)
    const float* We = (const float*)d_in[2];   // (16, 1536)
    float* out = (float*)d_out;
    const int T = in_sizes[0] / DD;            // 32768
    router_kernel<<<T / RPB, NTHR, 0, stream>>>(hs, Wm, We, out, T);
}